// Round 1
// baseline (1084.895 us; speedup 1.0000x reference)
//
#include <hip/hip_runtime.h>

// ---------------------------------------------------------------------------
// EBMAttention (B=8, S=2048, E=1024, H=1), fp32 in/out.
//   q_w   = query @ P^T + c        P = W_e @ Wq (precomputed), c = bq @ W_e^T
//   k     = key @ Wk^T + bk
//   v     = value @ Wv^T + bv      (stored transposed per batch: vT[b][d][s])
//   energy= q_w @ k^T  (per batch) -> written into d_out attn region (scratch)
//   attn  = softmax(-energy) row-wise (honoring mask==0 -> energy=-1e9)
//   out   = attn @ v   (per batch)
// Pre-softmax GEMMs use split-bf16 (hi+lo) 3-product MFMA for ~fp32 accuracy.
// ---------------------------------------------------------------------------

typedef __attribute__((ext_vector_type(8))) short short8;
typedef __attribute__((ext_vector_type(4))) float f32x4;

#define E_DIM 1024
#define S_LEN 2048
#define NB 8

// round-to-nearest-even fp32 -> bf16 bits
__device__ __forceinline__ unsigned short rne_bf(float x) {
    unsigned int u = __float_as_uint(x);
    return (unsigned short)((u + 0x7fffu + ((u >> 16) & 1u)) >> 16);
}

__device__ __forceinline__ void splitbf(float x, unsigned short& h, unsigned short& l) {
    unsigned int u = __float_as_uint(x);
    unsigned int rh = ((u + 0x7fffu + ((u >> 16) & 1u)) >> 16) << 16;
    h = (unsigned short)(rh >> 16);
    float r = x - __uint_as_float(rh);
    unsigned int v = __float_as_uint(r);
    l = (unsigned short)((v + 0x7fffu + ((v >> 16) & 1u)) >> 16);
}

// C[M,N] = A[M,K] @ B[N,K]^T (+ bias[n]).  A,B fp32 row-major, K-contiguous.
// SPLIT: 3-product hi/lo bf16 MFMA (near-fp32).  else single-product bf16.
// WMODE 0: C[r*N + c] (+batch bsC)   WMODE 1: C[(r>>11)*N*2048 + c*2048 + (r&2047)]
// Tile 128x128, BK=32, 4 waves (each 64x64 of 16x16x32 MFMA frags).
template <bool SPLIT, int WMODE>
__global__ __launch_bounds__(256) void gemm_split(
    const float* __restrict__ A, const float* __restrict__ B,
    float* __restrict__ C, const float* __restrict__ bias,
    int M, int N, int K,
    long long bsA, long long bsB, long long bsC)
{
    extern __shared__ unsigned short sm[];
    unsigned short* sAh = sm;            // [128][40] bf16 bits (pad 40 vs 32)
    unsigned short* sBh = sm + 5120;
    unsigned short* sAl = sm + 10240;    // only used when SPLIT
    unsigned short* sBl = sm + 15360;

    const int t = threadIdx.x;
    const int z = blockIdx.z;
    const float* Ab = A + (long long)z * bsA + (long long)blockIdx.y * 128 * K;
    const float* Bb = B + (long long)z * bsB + (long long)blockIdx.x * 128 * K;

    const int wv = t >> 6;
    const int lane = t & 63;
    const int wm = (wv >> 1) << 6;
    const int wn = (wv & 1) << 6;
    const int lr = lane & 15;
    const int ko = (lane >> 4) << 3;   // k offset (8 bf16 per lane-group)

    f32x4 acc[4][4] = {};

    for (int k0 = 0; k0 < K; k0 += 32) {
        __syncthreads();
        // ---- stage A and B tiles: fp32 -> (hi, lo) bf16 in LDS ----
#pragma unroll
        for (int i = 0; i < 4; ++i) {
            const int f = t + (i << 8);
            const int row = f >> 3;
            const int c4 = (f & 7) << 2;
            const float4 av = *(const float4*)(Ab + (long long)row * K + k0 + c4);
            const float4 bv = *(const float4*)(Bb + (long long)row * K + k0 + c4);
            if (SPLIT) {
                unsigned short h0, h1, h2, h3, l0, l1, l2, l3;
                splitbf(av.x, h0, l0); splitbf(av.y, h1, l1);
                splitbf(av.z, h2, l2); splitbf(av.w, h3, l3);
                uint2 hp, lp;
                hp.x = (unsigned)h0 | ((unsigned)h1 << 16);
                hp.y = (unsigned)h2 | ((unsigned)h3 << 16);
                lp.x = (unsigned)l0 | ((unsigned)l1 << 16);
                lp.y = (unsigned)l2 | ((unsigned)l3 << 16);
                *(uint2*)(sAh + row * 40 + c4) = hp;
                *(uint2*)(sAl + row * 40 + c4) = lp;
                splitbf(bv.x, h0, l0); splitbf(bv.y, h1, l1);
                splitbf(bv.z, h2, l2); splitbf(bv.w, h3, l3);
                hp.x = (unsigned)h0 | ((unsigned)h1 << 16);
                hp.y = (unsigned)h2 | ((unsigned)h3 << 16);
                lp.x = (unsigned)l0 | ((unsigned)l1 << 16);
                lp.y = (unsigned)l2 | ((unsigned)l3 << 16);
                *(uint2*)(sBh + row * 40 + c4) = hp;
                *(uint2*)(sBl + row * 40 + c4) = lp;
            } else {
                uint2 hp;
                hp.x = (unsigned)rne_bf(av.x) | ((unsigned)rne_bf(av.y) << 16);
                hp.y = (unsigned)rne_bf(av.z) | ((unsigned)rne_bf(av.w) << 16);
                *(uint2*)(sAh + row * 40 + c4) = hp;
                hp.x = (unsigned)rne_bf(bv.x) | ((unsigned)rne_bf(bv.y) << 16);
                hp.y = (unsigned)rne_bf(bv.z) | ((unsigned)rne_bf(bv.w) << 16);
                *(uint2*)(sBh + row * 40 + c4) = hp;
            }
        }
        __syncthreads();
        // ---- fragments + MFMA ----
        short8 ah[4], bh[4], al[4], bl[4];
#pragma unroll
        for (int m = 0; m < 4; ++m)
            ah[m] = *(const short8*)(sAh + (wm + m * 16 + lr) * 40 + ko);
#pragma unroll
        for (int n = 0; n < 4; ++n)
            bh[n] = *(const short8*)(sBh + (wn + n * 16 + lr) * 40 + ko);
        if (SPLIT) {
#pragma unroll
            for (int m = 0; m < 4; ++m)
                al[m] = *(const short8*)(sAl + (wm + m * 16 + lr) * 40 + ko);
#pragma unroll
            for (int n = 0; n < 4; ++n)
                bl[n] = *(const short8*)(sBl + (wn + n * 16 + lr) * 40 + ko);
        }
#pragma unroll
        for (int m = 0; m < 4; ++m) {
#pragma unroll
            for (int n = 0; n < 4; ++n) {
                acc[m][n] = __builtin_amdgcn_mfma_f32_16x16x32_bf16(ah[m], bh[n], acc[m][n], 0, 0, 0);
                if (SPLIT) {
                    acc[m][n] = __builtin_amdgcn_mfma_f32_16x16x32_bf16(ah[m], bl[n], acc[m][n], 0, 0, 0);
                    acc[m][n] = __builtin_amdgcn_mfma_f32_16x16x32_bf16(al[m], bh[n], acc[m][n], 0, 0, 0);
                }
            }
        }
    }

    // ---- epilogue: C/D layout col=lane&15, row=(lane>>4)*4+reg ----
    const int cr = (lane >> 4) << 2;
    const int cc = lane & 15;
    float* Cb = C + (long long)z * bsC;
#pragma unroll
    for (int m = 0; m < 4; ++m) {
#pragma unroll
        for (int n = 0; n < 4; ++n) {
            const int gc = blockIdx.x * 128 + wn + n * 16 + cc;
            const float badd = bias ? bias[gc] : 0.0f;
            const int gr0 = blockIdx.y * 128 + wm + m * 16 + cr;
#pragma unroll
            for (int i = 0; i < 4; ++i) {
                const float val = acc[m][n][i] + badd;
                if (WMODE == 0) {
                    Cb[(long long)(gr0 + i) * N + gc] = val;
                } else {
                    const int r = gr0 + i;
                    Cb[(long long)(r >> 11) * ((long long)N * 2048) +
                       (long long)gc * 2048 + (r & 2047)] = val;
                }
            }
        }
    }
}

// row-wise attn = softmax(-energy) with mask==0 -> energy=-1e9, in place.
__global__ __launch_bounds__(256) void softmax_rows(
    float* __restrict__ attn, const int* __restrict__ mask)
{
    const int row = blockIdx.x;
    const int q = row & (S_LEN - 1);
    const int t = threadIdx.x;
    const int lane = t & 63, wid = t >> 6;
    float* rp = attn + (long long)row * S_LEN;
    const int* mp = mask + (long long)q * S_LEN;

    float zv[8];
    float mx = -3.4e38f;
#pragma unroll
    for (int j = 0; j < 8; ++j) {
        const int idx = t + (j << 8);
        const float e = rp[idx];
        const int mv = mp[idx];
        const float zz = (mv != 0) ? -e : 1e9f;   // z = -masked_energy
        zv[j] = zz;
        mx = fmaxf(mx, zz);
    }
#pragma unroll
    for (int o = 32; o > 0; o >>= 1) mx = fmaxf(mx, __shfl_xor(mx, o));
    __shared__ float redm[4], reds[4];
    if (lane == 0) redm[wid] = mx;
    __syncthreads();
    mx = fmaxf(fmaxf(redm[0], redm[1]), fmaxf(redm[2], redm[3]));

    float s = 0.f;
#pragma unroll
    for (int j = 0; j < 8; ++j) { zv[j] = expf(zv[j] - mx); s += zv[j]; }
#pragma unroll
    for (int o = 32; o > 0; o >>= 1) s += __shfl_xor(s, o);
    if (lane == 0) reds[wid] = s;
    __syncthreads();
    s = reds[0] + reds[1] + reds[2] + reds[3];
    const float inv = 1.0f / s;
#pragma unroll
    for (int j = 0; j < 8; ++j) rp[t + (j << 8)] = zv[j] * inv;
}

// WqT[j][i] = Wq[i][j]  (1024x1024)
__global__ void transpose1024(const float* __restrict__ in, float* __restrict__ out)
{
    __shared__ float tile[32][33];
    const int bx = blockIdx.x << 5, by = blockIdx.y << 5;
    const int tx = threadIdx.x, ty = threadIdx.y;   // block (32,8)
#pragma unroll
    for (int i = 0; i < 4; ++i)
        tile[ty + 8 * i][tx] = in[(long long)(by + ty + 8 * i) * E_DIM + bx + tx];
    __syncthreads();
#pragma unroll
    for (int i = 0; i < 4; ++i)
        out[(long long)(bx + ty + 8 * i) * E_DIM + by + tx] = tile[tx][ty + 8 * i];
}

// c[i] = dot(bq, W_e[i,:])
__global__ __launch_bounds__(256) void bias_c_kernel(
    const float* __restrict__ We, const float* __restrict__ bq, float* __restrict__ c)
{
    const int i = blockIdx.x;
    const int t = threadIdx.x;
    float s = 0.f;
    for (int d = t; d < E_DIM; d += 256) s += bq[d] * We[(long long)i * E_DIM + d];
#pragma unroll
    for (int o = 32; o > 0; o >>= 1) s += __shfl_xor(s, o);
    __shared__ float red[4];
    if ((t & 63) == 0) red[t >> 6] = s;
    __syncthreads();
    if (t == 0) c[i] = red[0] + red[1] + red[2] + red[3];
}

extern "C" void kernel_launch(void* const* d_in, const int* in_sizes, int n_in,
                              void* d_out, int out_size, void* d_ws, size_t ws_size,
                              hipStream_t stream)
{
    const float* query = (const float*)d_in[0];
    const float* key   = (const float*)d_in[1];
    const float* value = (const float*)d_in[2];
    const int*   mask  = (const int*)d_in[3];
    const float* Wq    = (const float*)d_in[4];
    const float* bq    = (const float*)d_in[5];
    const float* Wk    = (const float*)d_in[6];
    const float* bk    = (const float*)d_in[7];
    const float* Wv    = (const float*)d_in[8];
    const float* bv    = (const float*)d_in[9];
    const float* We    = (const float*)d_in[10];

    float* out  = (float*)d_out;
    float* attn = out + (long long)NB * S_LEN * E_DIM;   // 16,777,216 floats in

    // workspace layout (floats): WqT 1M | P 1M | c 1K | k 16M | qw 16M | vT 16M
    float* ws   = (float*)d_ws;
    float* WqT  = ws;
    float* P    = WqT + 1048576;
    float* cvec = P + 1048576;
    float* kbuf = cvec + 1024;
    float* qw   = kbuf + 16777216;
    float* vT   = qw + 16777216;
    const size_t need = (size_t)(1048576 * 2 + 1024 + 16777216 * 3) * 4;
    if (ws_size < need) return;   // avoid OOB scrawl; will fail validation loudly

    transpose1024<<<dim3(32, 32), dim3(32, 8), 0, stream>>>(Wq, WqT);
    bias_c_kernel<<<1024, 256, 0, stream>>>(We, bq, cvec);

    // P = W_e @ Wq   (A=W_e, B=WqT)
    gemm_split<true, 0><<<dim3(8, 8, 1), 256, 40960, stream>>>(
        We, WqT, P, nullptr, 1024, 1024, 1024, 0, 0, 0);
    // k = key @ Wk^T + bk
    gemm_split<true, 0><<<dim3(8, 128, 1), 256, 40960, stream>>>(
        key, Wk, kbuf, bk, 16384, 1024, 1024, 0, 0, 0);
    // vT[b][d][s] = (value @ Wv^T + bv)^T   (plain bf16 precision is enough)
    gemm_split<false, 1><<<dim3(8, 128, 1), 256, 20480, stream>>>(
        value, Wv, vT, bv, 16384, 1024, 1024, 0, 0, 0);
    // q_w = query @ P^T + c
    gemm_split<true, 0><<<dim3(8, 128, 1), 256, 40960, stream>>>(
        query, P, qw, cvec, 16384, 1024, 1024, 0, 0, 0);
    // energy = q_w @ k^T per batch -> attn region (scratch)
    gemm_split<true, 0><<<dim3(16, 16, NB), 256, 40960, stream>>>(
        qw, kbuf, attn, nullptr, 2048, 2048, 1024,
        (long long)S_LEN * E_DIM, (long long)S_LEN * E_DIM, (long long)S_LEN * S_LEN);
    // attn = softmax(-energy) in place
    softmax_rows<<<NB * S_LEN, 256, 0, stream>>>(attn, mask);
    // out = attn @ v per batch  (A=attn fp32, B=vT)
    gemm_split<false, 0><<<dim3(8, 16, NB), 256, 20480, stream>>>(
        attn, vT, out, nullptr, 2048, 1024, 2048,
        (long long)S_LEN * S_LEN, (long long)E_DIM * S_LEN, (long long)S_LEN * E_DIM);

    (void)in_sizes; (void)n_in; (void)out_size;
}